// Round 7
// baseline (696.961 us; speedup 1.0000x reference)
//
#include <hip/hip_runtime.h>
#include <stdint.h>
#include <stddef.h>

// ---------------------------------------------------------------------------
// BayesianDTW forward on MI355X — R13: MEASUREMENT ROUND (double dispatch).
// Kernel = R11 VERBATIM (passed, 350us dispatch, absmax 8.0).
// kernel_launch enqueues dtw_pipe TWICE sharing the flag workspace:
//   D1: full inter-stripe protocol (flags start zeroed by harness reset()).
//   D2: identical work, but all flags are already set by D1 -> every
//       wait/poll satisfied instantly, edges read final values -> a
//       COMM-FREE replica with identical (idempotent) output.
// Purpose: 6 structural rounds (R9-R12) were all null/negative — within-wave
// models falsified. D2's duration separates the two surviving hypotheses:
//   H-comm (inter-stripe flag latency dominates): D2 ~100-180us,
//       headline ~550-630us, top-5 single ~345us cluster.
//   H-step (intrinsic ~600cy/step): D2 ~= D1 ~345us,
//       headline ~750-800us, top-5 shows both dispatches per iteration.
// ---------------------------------------------------------------------------

#define NBATCH  32
#define NA      512
#define NB      1024
#define NSTRIPE 8
#define SW      128          // cols per stripe
#define CH      8            // rows per chunk
#define NCHUNK  (NA / CH)    // 64
#define LSTR    128          // lds_o row stride (floats)
#define OROWS   513
#define OCOLS   1025
#define FSTRIDE 32           // flag padding: 128 B

#define NEGV    (-1e20f)
#define LOG2E   (1.4426950408889634f)
#define LN2     (0.6931471805599453f)
#define NEG2    (-1.4426950408889634e20f)   // NEGV in log2 units
#define FLAGTAG 0x5A000000u

#define EXP2F(x) __builtin_amdgcn_exp2f(x)   // v_exp_f32: 2^x
#define LOG2F(x) __builtin_amdgcn_logf(x)    // v_log_f32: log2(x)

__device__ __forceinline__ float lse3_2(float a, float b, float c) {
    // log2(2^a + 2^b + 2^c), log2 units. exp2 of the max is exactly 1 ->
    // only 2 transcendentals. NaN-free for finite inputs (diffs <= 0).
    float m  = fmaxf(fmaxf(a, b), c);                  // v_max3_f32
    float md = __builtin_amdgcn_fmed3f(a, b, c);       // v_med3_f32
    float mn = fminf(fminf(a, b), c);                  // v_min3_f32
    float ss = 1.0f + EXP2F(md - m) + EXP2F(mn - m);
    return m + LOG2F(ss);
}

__device__ __forceinline__ float rdlane(float v, int l) {
    return __int_as_float(__builtin_amdgcn_readlane(__float_as_int(v), l));
}

// lane i <- lane i-1 across the full wave, pure VALU:
// DPP row_shr:1 (16-lane rows) + readlane patches at lanes 16/32/48.
__device__ __forceinline__ float lane_shr1(float x, int lane) {
    int xi  = __float_as_int(x);
    int shr = __builtin_amdgcn_update_dpp(0, xi, 0x111, 0xf, 0xf, true);
    float v = __int_as_float(shr);
    float a15 = rdlane(x, 15), a31 = rdlane(x, 31), a47 = rdlane(x, 47);
    v = (lane == 16) ? a15 : v;
    v = (lane == 32) ? a31 : v;
    v = (lane == 48) ? a47 : v;
    return v;
}

__device__ __forceinline__ unsigned int ld_flag(unsigned int* fp) {
    return __hip_atomic_load(fp, __ATOMIC_RELAXED, __HIP_MEMORY_SCOPE_AGENT);
}
__device__ __forceinline__ void st_flag(unsigned int* fp, unsigned int v) {
    __hip_atomic_store(fp, v, __ATOMIC_RELAXED, __HIP_MEMORY_SCOPE_AGENT);
}
__device__ __forceinline__ float ld_edge(const float* p) {
    return __hip_atomic_load((float*)p, __ATOMIC_RELAXED, __HIP_MEMORY_SCOPE_AGENT);
}
__device__ __forceinline__ void st_edge(float* p, float v) {
    __hip_atomic_store(p, v, __ATOMIC_RELAXED, __HIP_MEMORY_SCOPE_AGENT);
}

__device__ __forceinline__ void wait_flag(unsigned int* fp, unsigned int need) {
    for (int k = 0; k < (1 << 22); ++k) {
        unsigned int v = ld_flag(fp);
        if ((v >> 24) == 0x5Au && (v & 0x00FFFFFFu) >= need) break;
    }
    asm volatile("" ::: "memory");
}

__global__ __launch_bounds__(64, 1)
void dtw_pipe(const float* __restrict__ W, float* __restrict__ out,
              unsigned int* __restrict__ flags)
{
    __shared__ float lds_o[128 * LSTR];   // output ring (ln units, final)

    const int lane = (int)threadIdx.x;
    const int bid  = (int)blockIdx.x;             // s*32 + b
    const int b    = bid & (NBATCH - 1);
    const int s    = bid >> 5;

    const float*  Wb  = W + ((size_t)b * NA) * NB + s * SW;
    float*        ob  = out + (size_t)b * OROWS * OCOLS;
    unsigned int* fmy = flags + (size_t)bid * FSTRIDE;
    unsigned int* fup = flags + (size_t)(bid - NBATCH) * FSTRIDE;

    // ---- boundary cells of output (final values; nobody reads these) ----
    ob[s * SW + 1 + lane]      = NEGV;
    ob[s * SW + 1 + 64 + lane] = NEGV;
    if (s == 0) {
        if (lane == 0) ob[0] = 0.0f;
        for (int r = lane; r < NA; r += 64)
            ob[(size_t)(r + 1) * OCOLS] = NEGV;
    }

    // ---- W register ring: prime rows 0..3 (clamped; r(t)=t-lane) ----
    float2 wr[4];
    #pragma unroll
    for (int k = 0; k < 4; ++k) {
        int rowc = k - lane;
        rowc = rowc < 0 ? 0 : rowc;
        wr[k] = *(const float2*)&Wb[(size_t)rowc * NB + 2 * lane];
    }

    // ---- edge prefetch (log2 units; lanes 0..7 hold 8 rows each) ----
    float evcur = -1e30f, evnxt = -1e30f, lres = -1e30f;
    if (s > 0) {
        wait_flag(fup, 1u);
        if (lane < CH)
            evcur = ld_edge(&ob[(size_t)(1 + lane) * OCOLS + s * SW]) * LOG2E;
        wait_flag(fup, 2u);
        if (lane < CH)
            evnxt = ld_edge(&ob[(size_t)(CH + 1 + lane) * OCOLS + s * SW]) * LOG2E;
        wait_flag(fup, 3u);
        if (lane < CH)
            lres  = ld_edge(&ob[(size_t)(2 * CH + 1 + lane) * OCOLS + s * SW]) * LOG2E;
    }

    asm volatile("s_waitcnt vmcnt(0)" ::: "memory");   // primes + edges done

    // ---- systolic state (log2 units, R3-proven) ----
    float topA = NEG2, topB = NEG2;   // mu[i-1, jA], mu[i-1, jB] (log2)
    float sh_in = NEG2;               // left neighbor's uB from prev step
    float tl_reg = NEG2;              // mu[i-1, jA-1]
    float ev_im1 = (s == 0) ? 0.0f : NEG2;  // lane0 topleft: mu[0,128s]·log2e
    unsigned int fpoll = 0;

    auto stepc = [&](int m, int tt, bool GATE, bool GNA) {
        const int t = 8 * m + tt;
        const int r = t - lane;
        if (tt == 1 && s > 0) fpoll = ld_flag(fup);      // hidden poll
        const float2 wv = wr[tt & 3];                    // copy, then refill
        {   // issue W load for row r+4 into the same slot
            int rowc = r + 4;
            rowc = rowc < 0 ? 0 : (rowc > NA - 1 ? NA - 1 : rowc);
            wr[tt & 3] = *(const float2*)&Wb[(size_t)rowc * NB + 2 * lane];
        }
        const float ev_i = rdlane(evcur, tt);
        // ---- carried chain (R3-proven) ----
        const float lf = (lane == 0) ? ev_i   : sh_in;   // mu[i, jA-1]
        const float tl = (lane == 0) ? ev_im1 : tl_reg;  // mu[i-1, jA-1]
        const float uA = fmaf(wv.x, LOG2E, lse3_2(topA, lf, tl));
        const float uB = fmaf(wv.y, LOG2E, lse3_2(topB, uA, topA));
        bool db = true;
        if (GATE) db = (r >= 0);
        if (GNA)  db = (r < NA);
        if (db) {                                        // off-chain store (ln)
            *(float2*)&lds_o[(r & 127) * LSTR + 2 * lane]
                = make_float2(uA * LN2, uB * LN2);
        }
        if (GATE) {
            const bool on = (r >= 0);
            topA   = on ? uA : NEG2;
            topB   = on ? uB : NEG2;
            tl_reg = on ? lf : NEG2;
        } else {
            topA = uA; topB = uB; tl_reg = lf;
        }
        ev_im1 = ev_i;
        sh_in  = lane_shr1(uB, lane);                    // pure-VALU pass
    };

    auto boundary = [&](int m) {
        const int f = m - 8;                  // chunk fully complete (skew 63)
        // 1) agent-scope edge-column dup for chunk f
        if (s < NSTRIPE - 1 && f >= 0 && lane < CH) {
            const int rw = (f << 3) + lane;
            const float evl = lds_o[(rw & 127) * LSTR + 127];
            st_edge(ob + (size_t)(rw + 1) * OCOLS + (s + 1) * SW, evl);
        }
        // 2) vmcnt(4): everything except the 4 newest vmem ops retired ->
        //    dup(f-1) from boundary m-1 drained -> publish v=f.
        asm volatile("s_waitcnt vmcnt(4)" ::: "memory");
        if (s < NSTRIPE - 1 && f >= 1 && lane == 0)
            st_flag(fmy, FLAGTAG + (unsigned)f);
        // 3) coalesced flush of chunk f
        if (f >= 0) {
            #pragma unroll
            for (int rr = 0; rr < CH; ++rr) {
                const int rw = (f << 3) + rr;
                const float v0 = lds_o[(rw & 127) * LSTR + lane];
                const float v1 = lds_o[(rw & 127) * LSTR + 64 + lane];
                float* orow = ob + (size_t)(rw + 1) * OCOLS + s * SW + 1;
                orow[lane]      = v0;
                orow[64 + lane] = v1;
            }
        }
        // 4) rotate edge regs; load chunk m+3 (need m+4, polled at tt==1)
        evcur = evnxt; evnxt = lres;
        const int c = m + 3;
        if (s > 0 && c < NCHUNK) {
            const unsigned need = (unsigned)(m + 4);
            if (!((fpoll >> 24) == 0x5Au && (fpoll & 0x00FFFFFFu) >= need))
                wait_flag(fup, need);
            lres = -1e30f;
            if (lane < CH)
                lres = ld_edge(&ob[(size_t)((c << 3) + 1 + lane) * OCOLS + s * SW])
                       * LOG2E;
        }
    };

    // ---- prologue: m=0..7 (some lanes r<0; full gating) ----
    for (int m = 0; m < 8; ++m) {
        #pragma unroll
        for (int tt = 0; tt < 8; ++tt) stepc(m, tt, true, false);
        boundary(m);
    }
    // ---- middle: m=8..63 (every lane 0<=r<NA; no gates) ----
    for (int m = 8; m < 64; ++m) {
        #pragma unroll
        for (int tt = 0; tt < 8; ++tt) stepc(m, tt, false, false);
        boundary(m);
    }
    // ---- epilogue: m=64..70 (store guard only) ----
    for (int m = 64; m < 71; ++m) {
        #pragma unroll
        for (int tt = 0; tt < 8; ++tt) stepc(m, tt, false, true);
        boundary(m);
    }
    // tail steps t = 568..574 (lane 63 finishes row 511 at t=574)
    #pragma unroll
    for (int tt = 0; tt < 7; ++tt) stepc(71, tt, false, true);

    // ---- final: chunk 63 ----
    {
        const int f = NCHUNK - 1;
        if (s < NSTRIPE - 1 && lane < CH) {
            const int rw = (f << 3) + lane;
            const float evl = lds_o[(rw & 127) * LSTR + 127];
            st_edge(ob + (size_t)(rw + 1) * OCOLS + (s + 1) * SW, evl);
        }
        asm volatile("s_waitcnt vmcnt(1)" ::: "memory");
        if (s < NSTRIPE - 1 && lane == 0)
            st_flag(fmy, FLAGTAG + (unsigned)f);          // chunks <= 62
        #pragma unroll
        for (int rr = 0; rr < CH; ++rr) {
            const int rw = (f << 3) + rr;
            const float v0 = lds_o[(rw & 127) * LSTR + lane];
            const float v1 = lds_o[(rw & 127) * LSTR + 64 + lane];
            float* orow = ob + (size_t)(rw + 1) * OCOLS + s * SW + 1;
            orow[lane]      = v0;
            orow[64 + lane] = v1;
        }
        asm volatile("s_waitcnt vmcnt(0)" ::: "memory");
        if (s < NSTRIPE - 1 && lane == 0)
            st_flag(fmy, FLAGTAG + (unsigned)NCHUNK);     // all 64 chunks
    }
}

extern "C" void kernel_launch(void* const* d_in, const int* in_sizes, int n_in,
                              void* d_out, int out_size, void* d_ws, size_t ws_size,
                              hipStream_t stream) {
    const float*  W     = (const float*)d_in[0];
    float*        out   = (float*)d_out;
    unsigned int* flags = (unsigned int*)d_ws;
    (void)in_sizes; (void)n_in; (void)out_size; (void)ws_size;
    // D1: full protocol (flags zeroed by harness reset between iterations).
    hipLaunchKernelGGL(dtw_pipe, dim3(NBATCH * NSTRIPE), dim3(64), 0, stream,
                       W, out, flags);
    // D2: comm-free replica — all flags already set by D1; identical
    // idempotent output. dur(D2) = intrinsic no-wait makespan (the probe).
    hipLaunchKernelGGL(dtw_pipe, dim3(NBATCH * NSTRIPE), dim3(64), 0, stream,
                       W, out, flags);
}

// Round 8
// 391.877 us; speedup vs baseline: 1.7785x; 1.7785x over previous
//
#include <hip/hip_runtime.h>
#include <stdint.h>
#include <stddef.h>

// ---------------------------------------------------------------------------
// BayesianDTW forward on MI355X — R14: 4 columns per lane (SW=256, 4 stripes).
// Evidence (R13 probe): wall ~= total wave-steps / ~430 steps/us, step time
// scales with active waves (D1 1247steps@274ns == D2 575steps@586ns). So the
// lever is TOTAL WAVE-STEPS: 256 waves x 575 -> 128 waves x 575 (4 cols/lane)
// = 73.6k wave-steps (was 147k), hops 7 -> 3.
// Math: R3/R11-PROVEN log2 lse3 recurrence, generalized to 4 serial cells:
//   u_k = w_k + lse3(top_k, u_{k-1}, top_{k-1}), u_{-1}=lf, top_{-1}=tl.
// Protocol R11-verbatim (CH=8, hidden fpoll at tt==1, vmcnt-counted publish,
// 3-deep edge prefetch, agent-scope edge dup).
// W: one aligned dwordx4/lane/step (lane's own 4 cols), 4-deep register ring.
// Output: 128-row x 260-float dynamic-LDS ring (130KB), boundary flush.
// ---------------------------------------------------------------------------

#define NBATCH  32
#define NA      512
#define NB      1024
#define NSTRIPE 4
#define SW      256          // cols per stripe (4 per lane)
#define CH      8            // rows per chunk
#define NCHUNK  (NA / CH)    // 64
#define LSTR    260          // lds_o row stride (floats; 256 + 4 pad)
#define OROWS   513
#define OCOLS   1025
#define FSTRIDE 32           // flag padding: 128 B

#define NEGV    (-1e20f)
#define LOG2E   (1.4426950408889634f)
#define LN2     (0.6931471805599453f)
#define NEG2    (-1.4426950408889634e20f)   // NEGV in log2 units
#define FLAGTAG 0x5A000000u

#define EXP2F(x) __builtin_amdgcn_exp2f(x)   // v_exp_f32: 2^x
#define LOG2F(x) __builtin_amdgcn_logf(x)    // v_log_f32: log2(x)

__device__ __forceinline__ float lse3_2(float a, float b, float c) {
    // log2(2^a + 2^b + 2^c), log2 units. exp2 of the max is exactly 1 ->
    // only 2 transcendentals. NaN-free for finite inputs (diffs <= 0).
    float m  = fmaxf(fmaxf(a, b), c);                  // v_max3_f32
    float md = __builtin_amdgcn_fmed3f(a, b, c);       // v_med3_f32
    float mn = fminf(fminf(a, b), c);                  // v_min3_f32
    float ss = 1.0f + EXP2F(md - m) + EXP2F(mn - m);
    return m + LOG2F(ss);
}

__device__ __forceinline__ float rdlane(float v, int l) {
    return __int_as_float(__builtin_amdgcn_readlane(__float_as_int(v), l));
}

// lane i <- lane i-1 across the full wave, pure VALU:
// DPP row_shr:1 (16-lane rows) + readlane patches at lanes 16/32/48.
__device__ __forceinline__ float lane_shr1(float x, int lane) {
    int xi  = __float_as_int(x);
    int shr = __builtin_amdgcn_update_dpp(0, xi, 0x111, 0xf, 0xf, true);
    float v = __int_as_float(shr);
    float a15 = rdlane(x, 15), a31 = rdlane(x, 31), a47 = rdlane(x, 47);
    v = (lane == 16) ? a15 : v;
    v = (lane == 32) ? a31 : v;
    v = (lane == 48) ? a47 : v;
    return v;
}

__device__ __forceinline__ unsigned int ld_flag(unsigned int* fp) {
    return __hip_atomic_load(fp, __ATOMIC_RELAXED, __HIP_MEMORY_SCOPE_AGENT);
}
__device__ __forceinline__ void st_flag(unsigned int* fp, unsigned int v) {
    __hip_atomic_store(fp, v, __ATOMIC_RELAXED, __HIP_MEMORY_SCOPE_AGENT);
}
__device__ __forceinline__ float ld_edge(const float* p) {
    return __hip_atomic_load((float*)p, __ATOMIC_RELAXED, __HIP_MEMORY_SCOPE_AGENT);
}
__device__ __forceinline__ void st_edge(float* p, float v) {
    __hip_atomic_store(p, v, __ATOMIC_RELAXED, __HIP_MEMORY_SCOPE_AGENT);
}

__device__ __forceinline__ void wait_flag(unsigned int* fp, unsigned int need) {
    for (int k = 0; k < (1 << 22); ++k) {
        unsigned int v = ld_flag(fp);
        if ((v >> 24) == 0x5Au && (v & 0x00FFFFFFu) >= need) break;
    }
    asm volatile("" ::: "memory");
}

__global__ __launch_bounds__(64, 1)
void dtw_pipe(const float* __restrict__ W, float* __restrict__ out,
              unsigned int* __restrict__ flags)
{
    extern __shared__ float lds_o[];   // 128 x LSTR output ring (ln units)

    const int lane = (int)threadIdx.x;
    const int bid  = (int)blockIdx.x;             // s*32 + b
    const int b    = bid & (NBATCH - 1);
    const int s    = bid >> 5;

    const float*  Wb  = W + ((size_t)b * NA) * NB + s * SW;
    float*        ob  = out + (size_t)b * OROWS * OCOLS;
    unsigned int* fmy = flags + (size_t)bid * FSTRIDE;
    unsigned int* fup = flags + (size_t)(bid - NBATCH) * FSTRIDE;

    // ---- boundary cells of output (final values; nobody reads these) ----
    // row 0 of this stripe's 256 cols:
    #pragma unroll
    for (int k = 0; k < 4; ++k)
        ob[s * SW + 1 + 4 * lane + k] = NEGV;
    if (s == 0) {
        if (lane == 0) ob[0] = 0.0f;
        for (int r = lane; r < NA; r += 64)
            ob[(size_t)(r + 1) * OCOLS] = NEGV;
    }

    // ---- W register ring: prime rows 0..3 (clamped; r(t)=t-lane) ----
    // lane's own 4 cols: one aligned dwordx4 per row.
    float4 wr[4];
    #pragma unroll
    for (int k = 0; k < 4; ++k) {
        int rowc = k - lane;
        rowc = rowc < 0 ? 0 : rowc;
        wr[k] = *(const float4*)&Wb[(size_t)rowc * NB + 4 * lane];
    }

    // ---- edge prefetch (log2 units; lanes 0..7 hold 8 rows each) ----
    float evcur = -1e30f, evnxt = -1e30f, lres = -1e30f;
    if (s > 0) {
        wait_flag(fup, 1u);
        if (lane < CH)
            evcur = ld_edge(&ob[(size_t)(1 + lane) * OCOLS + s * SW]) * LOG2E;
        wait_flag(fup, 2u);
        if (lane < CH)
            evnxt = ld_edge(&ob[(size_t)(CH + 1 + lane) * OCOLS + s * SW]) * LOG2E;
        wait_flag(fup, 3u);
        if (lane < CH)
            lres  = ld_edge(&ob[(size_t)(2 * CH + 1 + lane) * OCOLS + s * SW]) * LOG2E;
    }

    asm volatile("s_waitcnt vmcnt(0)" ::: "memory");   // primes + edges done

    // ---- systolic state (log2 units, R3-proven, 4 cells/lane) ----
    float top0 = NEG2, top1 = NEG2, top2 = NEG2, top3 = NEG2;
    float sh_in = NEG2;               // left neighbor's u3 from prev step
    float tl_reg = NEG2;              // mu[i-1, col0-1]
    float ev_im1 = (s == 0) ? 0.0f : NEG2;  // lane0 topleft
    unsigned int fpoll = 0;

    auto stepc = [&](int m, int tt, bool GATE, bool GNA) {
        const int t = 8 * m + tt;
        const int r = t - lane;
        if (tt == 1 && s > 0) fpoll = ld_flag(fup);      // hidden poll
        const float4 wv = wr[tt & 3];                    // copy, then refill
        {   // issue W load for row r+4 into the same slot
            int rowc = r + 4;
            rowc = rowc < 0 ? 0 : (rowc > NA - 1 ? NA - 1 : rowc);
            wr[tt & 3] = *(const float4*)&Wb[(size_t)rowc * NB + 4 * lane];
        }
        const float ev_i = rdlane(evcur, tt);
        // ---- carried chain: 4 serial cells (R3-proven algebra) ----
        const float lf = (lane == 0) ? ev_i   : sh_in;   // mu[i, col0-1]
        const float tl = (lane == 0) ? ev_im1 : tl_reg;  // mu[i-1, col0-1]
        const float u0 = fmaf(wv.x, LOG2E, lse3_2(top0, lf, tl));
        const float u1 = fmaf(wv.y, LOG2E, lse3_2(top1, u0, top0));
        const float u2 = fmaf(wv.z, LOG2E, lse3_2(top2, u1, top1));
        const float u3 = fmaf(wv.w, LOG2E, lse3_2(top3, u2, top2));
        bool db = true;
        if (GATE) db = (r >= 0);
        if (GNA)  db = (r < NA);
        if (db) {   // off-chain store (ln units), 16B aligned ds_write_b128
            *(float4*)&lds_o[(r & 127) * LSTR + 4 * lane]
                = make_float4(u0 * LN2, u1 * LN2, u2 * LN2, u3 * LN2);
        }
        if (GATE) {
            const bool on = (r >= 0);
            top0 = on ? u0 : NEG2;  top1 = on ? u1 : NEG2;
            top2 = on ? u2 : NEG2;  top3 = on ? u3 : NEG2;
            tl_reg = on ? lf : NEG2;
        } else {
            top0 = u0; top1 = u1; top2 = u2; top3 = u3; tl_reg = lf;
        }
        ev_im1 = ev_i;
        sh_in  = lane_shr1(u3, lane);                    // pure-VALU pass
    };

    auto boundary = [&](int m) {
        const int f = m - 8;                  // chunk fully complete (skew 63)
        // 1) agent-scope edge-column dup for chunk f (last col of stripe)
        if (s < NSTRIPE - 1 && f >= 0 && lane < CH) {
            const int rw = (f << 3) + lane;
            const float evl = lds_o[(rw & 127) * LSTR + (SW - 1)];
            st_edge(ob + (size_t)(rw + 1) * OCOLS + (s + 1) * SW, evl);
        }
        // 2) vmcnt(4): everything except the 4 newest vmem ops retired
        //    (this dup + 3 newest W loads) -> dup(f-1) from boundary m-1
        //    drained -> publish v=f (claims chunks <= f-1 visible).
        asm volatile("s_waitcnt vmcnt(4)" ::: "memory");
        if (s < NSTRIPE - 1 && f >= 1 && lane == 0)
            st_flag(fmy, FLAGTAG + (unsigned)f);
        // 3) flush chunk f: 8 rows x 256 cols; lane stores its 4 cols
        //    (scalar stores: global row base is odd -> 16B-misaligned).
        if (f >= 0) {
            #pragma unroll
            for (int rr = 0; rr < CH; ++rr) {
                const int rw = (f << 3) + rr;
                const float4 v = *(const float4*)
                    &lds_o[(rw & 127) * LSTR + 4 * lane];
                float* orow = ob + (size_t)(rw + 1) * OCOLS + s * SW + 1
                            + 4 * lane;
                orow[0] = v.x; orow[1] = v.y; orow[2] = v.z; orow[3] = v.w;
            }
        }
        // 4) rotate edge regs; load chunk m+3 (need m+4, polled at tt==1)
        evcur = evnxt; evnxt = lres;
        const int c = m + 3;
        if (s > 0 && c < NCHUNK) {
            const unsigned need = (unsigned)(m + 4);
            if (!((fpoll >> 24) == 0x5Au && (fpoll & 0x00FFFFFFu) >= need))
                wait_flag(fup, need);
            lres = -1e30f;
            if (lane < CH)
                lres = ld_edge(&ob[(size_t)((c << 3) + 1 + lane) * OCOLS + s * SW])
                       * LOG2E;
        }
    };

    // ---- prologue: m=0..7 (some lanes r<0; full gating) ----
    for (int m = 0; m < 8; ++m) {
        #pragma unroll
        for (int tt = 0; tt < 8; ++tt) stepc(m, tt, true, false);
        boundary(m);
    }
    // ---- middle: m=8..63 (every lane 0<=r<NA; no gates) ----
    for (int m = 8; m < 64; ++m) {
        #pragma unroll
        for (int tt = 0; tt < 8; ++tt) stepc(m, tt, false, false);
        boundary(m);
    }
    // ---- epilogue: m=64..70 (store guard only) ----
    for (int m = 64; m < 71; ++m) {
        #pragma unroll
        for (int tt = 0; tt < 8; ++tt) stepc(m, tt, false, true);
        boundary(m);
    }
    // tail steps t = 568..574 (lane 63 finishes row 511 at t=574)
    #pragma unroll
    for (int tt = 0; tt < 7; ++tt) stepc(71, tt, false, true);

    // ---- final: chunk 63 ----
    {
        const int f = NCHUNK - 1;
        if (s < NSTRIPE - 1 && lane < CH) {
            const int rw = (f << 3) + lane;
            const float evl = lds_o[(rw & 127) * LSTR + (SW - 1)];
            st_edge(ob + (size_t)(rw + 1) * OCOLS + (s + 1) * SW, evl);
        }
        asm volatile("s_waitcnt vmcnt(1)" ::: "memory");
        if (s < NSTRIPE - 1 && lane == 0)
            st_flag(fmy, FLAGTAG + (unsigned)f);          // chunks <= 62
        #pragma unroll
        for (int rr = 0; rr < CH; ++rr) {
            const int rw = (f << 3) + rr;
            const float4 v = *(const float4*)
                &lds_o[(rw & 127) * LSTR + 4 * lane];
            float* orow = ob + (size_t)(rw + 1) * OCOLS + s * SW + 1
                        + 4 * lane;
            orow[0] = v.x; orow[1] = v.y; orow[2] = v.z; orow[3] = v.w;
        }
        asm volatile("s_waitcnt vmcnt(0)" ::: "memory");
        if (s < NSTRIPE - 1 && lane == 0)
            st_flag(fmy, FLAGTAG + (unsigned)NCHUNK);     // all 64 chunks
    }
}

extern "C" void kernel_launch(void* const* d_in, const int* in_sizes, int n_in,
                              void* d_out, int out_size, void* d_ws, size_t ws_size,
                              hipStream_t stream) {
    const float*  W     = (const float*)d_in[0];
    float*        out   = (float*)d_out;
    unsigned int* flags = (unsigned int*)d_ws;
    (void)in_sizes; (void)n_in; (void)out_size; (void)ws_size;
    hipLaunchKernelGGL(dtw_pipe, dim3(NBATCH * NSTRIPE), dim3(64),
                       128 * LSTR * sizeof(float), stream,
                       W, out, flags);
}

// Round 9
// 382.040 us; speedup vs baseline: 1.8243x; 1.0257x over previous
//
#include <hip/hip_runtime.h>
#include <stdint.h>
#include <stddef.h>

// ---------------------------------------------------------------------------
// BayesianDTW forward on MI355X — R15: compact coherent-edge staging.
// Base: R14 (passed, 312us, absmax 8.0; 4 cols/lane, SW=256, 4 stripes).
// Evidence: across R7/R10/R11/R12/R13-D2 the agent-scope coherence traffic
// sits at 0.77-0.87 cache-line-ops/ns (18 distinct lines per boundary per
// wave: 8 st_edge @4KB stride + 8 ld_edge + flag st + poll); R14 (the only
// faster kernel) is the only one that halved it (0.47/ns). Hypothesis: the
// cross-XCD coherence fabric is the shared serializer (explains the ~460
// cy/step fixed cost and the R13-D2 anomaly).
// R15 single variable: route edge values through a COMPACT workspace buffer
// (8 contiguous floats = 1 line per (bid,chunk)) -> ~18 -> ~5 line-ops per
// boundary. The strided out-column dup is deleted (the ordinary flush
// already writes that column: its last col IS (s+1)*SW). Flag/vmcnt
// protocol unchanged. Runtime ws_size guard: falls back to R14-verbatim
// path if workspace < 272KB (zero correctness risk).
// ---------------------------------------------------------------------------

#define NBATCH  32
#define NA      512
#define NB      1024
#define NSTRIPE 4
#define SW      256          // cols per stripe (4 per lane)
#define CH      8            // rows per chunk
#define NCHUNK  (NA / CH)    // 64
#define LSTR    260          // lds_o row stride (floats; 256 + 4 pad)
#define OROWS   513
#define OCOLS   1025
#define FSTRIDE 32           // flag padding: 128 B
#define NBID    (NBATCH * NSTRIPE)
// edge staging: floats, [bid][chunk][8] contiguous (32B per chunk-line)
#define ESTAGE_OFF_U32 (NBID * FSTRIDE)              // after flags (16KB)
#define WS_NEEDED ((size_t)(NBID * FSTRIDE * 4 + NBID * NCHUNK * 8 * 4))

#define NEGV    (-1e20f)
#define LOG2E   (1.4426950408889634f)
#define LN2     (0.6931471805599453f)
#define NEG2    (-1.4426950408889634e20f)   // NEGV in log2 units
#define FLAGTAG 0x5A000000u

#define EXP2F(x) __builtin_amdgcn_exp2f(x)   // v_exp_f32: 2^x
#define LOG2F(x) __builtin_amdgcn_logf(x)    // v_log_f32: log2(x)

__device__ __forceinline__ float lse3_2(float a, float b, float c) {
    // log2(2^a + 2^b + 2^c), log2 units. exp2 of the max is exactly 1 ->
    // only 2 transcendentals. NaN-free for finite inputs (diffs <= 0).
    float m  = fmaxf(fmaxf(a, b), c);                  // v_max3_f32
    float md = __builtin_amdgcn_fmed3f(a, b, c);       // v_med3_f32
    float mn = fminf(fminf(a, b), c);                  // v_min3_f32
    float ss = 1.0f + EXP2F(md - m) + EXP2F(mn - m);
    return m + LOG2F(ss);
}

__device__ __forceinline__ float rdlane(float v, int l) {
    return __int_as_float(__builtin_amdgcn_readlane(__float_as_int(v), l));
}

// lane i <- lane i-1 across the full wave, pure VALU:
// DPP row_shr:1 (16-lane rows) + readlane patches at lanes 16/32/48.
__device__ __forceinline__ float lane_shr1(float x, int lane) {
    int xi  = __float_as_int(x);
    int shr = __builtin_amdgcn_update_dpp(0, xi, 0x111, 0xf, 0xf, true);
    float v = __int_as_float(shr);
    float a15 = rdlane(x, 15), a31 = rdlane(x, 31), a47 = rdlane(x, 47);
    v = (lane == 16) ? a15 : v;
    v = (lane == 32) ? a31 : v;
    v = (lane == 48) ? a47 : v;
    return v;
}

__device__ __forceinline__ unsigned int ld_flag(unsigned int* fp) {
    return __hip_atomic_load(fp, __ATOMIC_RELAXED, __HIP_MEMORY_SCOPE_AGENT);
}
__device__ __forceinline__ void st_flag(unsigned int* fp, unsigned int v) {
    __hip_atomic_store(fp, v, __ATOMIC_RELAXED, __HIP_MEMORY_SCOPE_AGENT);
}
__device__ __forceinline__ float ld_edge(const float* p) {
    return __hip_atomic_load((float*)p, __ATOMIC_RELAXED, __HIP_MEMORY_SCOPE_AGENT);
}
__device__ __forceinline__ void st_edge(float* p, float v) {
    __hip_atomic_store(p, v, __ATOMIC_RELAXED, __HIP_MEMORY_SCOPE_AGENT);
}

__device__ __forceinline__ void wait_flag(unsigned int* fp, unsigned int need) {
    for (int k = 0; k < (1 << 22); ++k) {
        unsigned int v = ld_flag(fp);
        if ((v >> 24) == 0x5Au && (v & 0x00FFFFFFu) >= need) break;
    }
    asm volatile("" ::: "memory");
}

__global__ __launch_bounds__(64, 1)
void dtw_pipe(const float* __restrict__ W, float* __restrict__ out,
              unsigned int* __restrict__ flags, int use_stage)
{
    extern __shared__ float lds_o[];   // 128 x LSTR output ring (ln units)

    const int lane = (int)threadIdx.x;
    const int bid  = (int)blockIdx.x;             // s*32 + b
    const int b    = bid & (NBATCH - 1);
    const int s    = bid >> 5;

    const float*  Wb  = W + ((size_t)b * NA) * NB + s * SW;
    float*        ob  = out + (size_t)b * OROWS * OCOLS;
    unsigned int* fmy = flags + (size_t)bid * FSTRIDE;
    unsigned int* fup = flags + (size_t)(bid - NBATCH) * FSTRIDE;
    float*        emy = (float*)(flags + ESTAGE_OFF_U32) + (size_t)bid * NCHUNK * 8;
    float*        eup = (float*)(flags + ESTAGE_OFF_U32) + (size_t)(bid - NBATCH) * NCHUNK * 8;

    // ---- boundary cells of output (final values; nobody reads these) ----
    #pragma unroll
    for (int k = 0; k < 4; ++k)
        ob[s * SW + 1 + 4 * lane + k] = NEGV;
    if (s == 0) {
        if (lane == 0) ob[0] = 0.0f;
        for (int r = lane; r < NA; r += 64)
            ob[(size_t)(r + 1) * OCOLS] = NEGV;
    }

    // ---- W register ring: prime rows 0..3 (clamped; r(t)=t-lane) ----
    float4 wr[4];
    #pragma unroll
    for (int k = 0; k < 4; ++k) {
        int rowc = k - lane;
        rowc = rowc < 0 ? 0 : rowc;
        wr[k] = *(const float4*)&Wb[(size_t)rowc * NB + 4 * lane];
    }

    // ---- edge prefetch (log2 units; lanes 0..7 hold 8 rows each) ----
    float evcur = -1e30f, evnxt = -1e30f, lres = -1e30f;
    if (s > 0) {
        wait_flag(fup, 1u);
        if (lane < CH)
            evcur = (use_stage ? ld_edge(&eup[0 * 8 + lane])
                               : ld_edge(&ob[(size_t)(1 + lane) * OCOLS + s * SW]))
                    * LOG2E;
        wait_flag(fup, 2u);
        if (lane < CH)
            evnxt = (use_stage ? ld_edge(&eup[1 * 8 + lane])
                               : ld_edge(&ob[(size_t)(CH + 1 + lane) * OCOLS + s * SW]))
                    * LOG2E;
        wait_flag(fup, 3u);
        if (lane < CH)
            lres  = (use_stage ? ld_edge(&eup[2 * 8 + lane])
                               : ld_edge(&ob[(size_t)(2 * CH + 1 + lane) * OCOLS + s * SW]))
                    * LOG2E;
    }

    asm volatile("s_waitcnt vmcnt(0)" ::: "memory");   // primes + edges done

    // ---- systolic state (log2 units, R3-proven, 4 cells/lane) ----
    float top0 = NEG2, top1 = NEG2, top2 = NEG2, top3 = NEG2;
    float sh_in = NEG2;               // left neighbor's u3 from prev step
    float tl_reg = NEG2;              // mu[i-1, col0-1]
    float ev_im1 = (s == 0) ? 0.0f : NEG2;  // lane0 topleft
    unsigned int fpoll = 0;

    auto stepc = [&](int m, int tt, bool GATE, bool GNA) {
        const int t = 8 * m + tt;
        const int r = t - lane;
        if (tt == 1 && s > 0) fpoll = ld_flag(fup);      // hidden poll
        const float4 wv = wr[tt & 3];                    // copy, then refill
        {   // issue W load for row r+4 into the same slot
            int rowc = r + 4;
            rowc = rowc < 0 ? 0 : (rowc > NA - 1 ? NA - 1 : rowc);
            wr[tt & 3] = *(const float4*)&Wb[(size_t)rowc * NB + 4 * lane];
        }
        const float ev_i = rdlane(evcur, tt);
        // ---- carried chain: 4 serial cells (R3-proven algebra) ----
        const float lf = (lane == 0) ? ev_i   : sh_in;   // mu[i, col0-1]
        const float tl = (lane == 0) ? ev_im1 : tl_reg;  // mu[i-1, col0-1]
        const float u0 = fmaf(wv.x, LOG2E, lse3_2(top0, lf, tl));
        const float u1 = fmaf(wv.y, LOG2E, lse3_2(top1, u0, top0));
        const float u2 = fmaf(wv.z, LOG2E, lse3_2(top2, u1, top1));
        const float u3 = fmaf(wv.w, LOG2E, lse3_2(top3, u2, top2));
        bool db = true;
        if (GATE) db = (r >= 0);
        if (GNA)  db = (r < NA);
        if (db) {   // off-chain store (ln units), 16B aligned ds_write_b128
            *(float4*)&lds_o[(r & 127) * LSTR + 4 * lane]
                = make_float4(u0 * LN2, u1 * LN2, u2 * LN2, u3 * LN2);
        }
        if (GATE) {
            const bool on = (r >= 0);
            top0 = on ? u0 : NEG2;  top1 = on ? u1 : NEG2;
            top2 = on ? u2 : NEG2;  top3 = on ? u3 : NEG2;
            tl_reg = on ? lf : NEG2;
        } else {
            top0 = u0; top1 = u1; top2 = u2; top3 = u3; tl_reg = lf;
        }
        ev_im1 = ev_i;
        sh_in  = lane_shr1(u3, lane);                    // pure-VALU pass
    };

    auto boundary = [&](int m) {
        const int f = m - 8;                  // chunk fully complete (skew 63)
        // 1) coherent edge publish for chunk f:
        //    staged: ONE 32B line (8 contiguous floats) per chunk.
        //    fallback: R14's 8-line strided column dup.
        if (s < NSTRIPE - 1 && f >= 0 && lane < CH) {
            const int rw = (f << 3) + lane;
            const float evl = lds_o[(rw & 127) * LSTR + (SW - 1)];
            if (use_stage) st_edge(&emy[(size_t)f * 8 + lane], evl);
            else st_edge(ob + (size_t)(rw + 1) * OCOLS + (s + 1) * SW, evl);
        }
        // 2) vmcnt(4): everything except the 4 newest vmem ops retired
        //    (this edge publish + 3 newest W loads) -> publish(f-1) from
        //    boundary m-1 drained -> flag v=f claims chunks <= f-1 visible.
        asm volatile("s_waitcnt vmcnt(4)" ::: "memory");
        if (s < NSTRIPE - 1 && f >= 1 && lane == 0)
            st_flag(fmy, FLAGTAG + (unsigned)f);
        // 3) flush chunk f: 8 rows x 256 cols; lane stores its 4 cols.
        //    (covers col (s+1)*SW too: k=3 of lane 63 -> out stays complete)
        if (f >= 0) {
            #pragma unroll
            for (int rr = 0; rr < CH; ++rr) {
                const int rw = (f << 3) + rr;
                const float4 v = *(const float4*)
                    &lds_o[(rw & 127) * LSTR + 4 * lane];
                float* orow = ob + (size_t)(rw + 1) * OCOLS + s * SW + 1
                            + 4 * lane;
                orow[0] = v.x; orow[1] = v.y; orow[2] = v.z; orow[3] = v.w;
            }
        }
        // 4) rotate edge regs; load chunk m+3 (need m+4, polled at tt==1)
        evcur = evnxt; evnxt = lres;
        const int c = m + 3;
        if (s > 0 && c < NCHUNK) {
            const unsigned need = (unsigned)(m + 4);
            if (!((fpoll >> 24) == 0x5Au && (fpoll & 0x00FFFFFFu) >= need))
                wait_flag(fup, need);
            lres = -1e30f;
            if (lane < CH)
                lres = (use_stage ? ld_edge(&eup[(size_t)c * 8 + lane])
                                  : ld_edge(&ob[(size_t)((c << 3) + 1 + lane) * OCOLS + s * SW]))
                       * LOG2E;
        }
    };

    // ---- prologue: m=0..7 (some lanes r<0; full gating) ----
    for (int m = 0; m < 8; ++m) {
        #pragma unroll
        for (int tt = 0; tt < 8; ++tt) stepc(m, tt, true, false);
        boundary(m);
    }
    // ---- middle: m=8..63 (every lane 0<=r<NA; no gates) ----
    for (int m = 8; m < 64; ++m) {
        #pragma unroll
        for (int tt = 0; tt < 8; ++tt) stepc(m, tt, false, false);
        boundary(m);
    }
    // ---- epilogue: m=64..70 (store guard only) ----
    for (int m = 64; m < 71; ++m) {
        #pragma unroll
        for (int tt = 0; tt < 8; ++tt) stepc(m, tt, false, true);
        boundary(m);
    }
    // tail steps t = 568..574 (lane 63 finishes row 511 at t=574)
    #pragma unroll
    for (int tt = 0; tt < 7; ++tt) stepc(71, tt, false, true);

    // ---- final: chunk 63 ----
    {
        const int f = NCHUNK - 1;
        if (s < NSTRIPE - 1 && lane < CH) {
            const int rw = (f << 3) + lane;
            const float evl = lds_o[(rw & 127) * LSTR + (SW - 1)];
            if (use_stage) st_edge(&emy[(size_t)f * 8 + lane], evl);
            else st_edge(ob + (size_t)(rw + 1) * OCOLS + (s + 1) * SW, evl);
        }
        asm volatile("s_waitcnt vmcnt(1)" ::: "memory");
        if (s < NSTRIPE - 1 && lane == 0)
            st_flag(fmy, FLAGTAG + (unsigned)f);          // chunks <= 62
        #pragma unroll
        for (int rr = 0; rr < CH; ++rr) {
            const int rw = (f << 3) + rr;
            const float4 v = *(const float4*)
                &lds_o[(rw & 127) * LSTR + 4 * lane];
            float* orow = ob + (size_t)(rw + 1) * OCOLS + s * SW + 1
                        + 4 * lane;
            orow[0] = v.x; orow[1] = v.y; orow[2] = v.z; orow[3] = v.w;
        }
        asm volatile("s_waitcnt vmcnt(0)" ::: "memory");
        if (s < NSTRIPE - 1 && lane == 0)
            st_flag(fmy, FLAGTAG + (unsigned)NCHUNK);     // all 64 chunks
    }
}

extern "C" void kernel_launch(void* const* d_in, const int* in_sizes, int n_in,
                              void* d_out, int out_size, void* d_ws, size_t ws_size,
                              hipStream_t stream) {
    const float*  W     = (const float*)d_in[0];
    float*        out   = (float*)d_out;
    unsigned int* flags = (unsigned int*)d_ws;
    (void)in_sizes; (void)n_in; (void)out_size;
    const int use_stage = (ws_size >= WS_NEEDED) ? 1 : 0;
    hipLaunchKernelGGL(dtw_pipe, dim3(NBID), dim3(64),
                       128 * LSTR * sizeof(float), stream,
                       W, out, flags, use_stage);
}